// Round 1
// baseline (183.051 us; speedup 1.0000x reference)
//
#include <hip/hip_runtime.h>

// Problem constants (from reference setup_inputs):
//   B=512, L=512, H=2*50=100, C=40.0
// data: float32 (B,L,H); aspect_Index/aspect_len/sents_len: int (B,)
// out = data * mask(b,l)  broadcast over H.
//
// mask(b,l):
//   a_end = aspect_Index[b] + aspect_len[b]
//   if l < a_end:          1 - (a_end - l)/C
//   elif l < sents_len[b]: 1 - (l - aspect_Index[b])/C
//   else:                  0

constexpr int kL = 512;
constexpr int kH = 100;
constexpr float kInvC = 1.0f / 40.0f;

__global__ __launch_bounds__(256) void mask_mul_kernel(
    const float4* __restrict__ data,
    const int* __restrict__ a_idx,
    const int* __restrict__ a_len,
    const int* __restrict__ s_len,
    float4* __restrict__ out)
{
    const int idx = blockIdx.x * blockDim.x + threadIdx.x;   // float4 index
    const int e   = idx * 4;                                  // element index
    // H=100 divisible by 4 => all 4 elements of this float4 share one (b,l)
    const int bl = e / kH;              // row index (compiler magic-mul by 100)
    const int l  = bl & (kL - 1);
    const int b  = bl >> 9;             // L=512

    const int aI = a_idx[b];
    const int aE = aI + a_len[b];
    const int sL = s_len[b];

    float m;
    if (l < aE)       m = 1.0f - (float)(aE - l) * kInvC;
    else if (l < sL)  m = 1.0f - (float)(l - aI) * kInvC;
    else              m = 0.0f;

    float4 v = data[idx];
    v.x *= m; v.y *= m; v.z *= m; v.w *= m;
    out[idx] = v;
}

extern "C" void kernel_launch(void* const* d_in, const int* in_sizes, int n_in,
                              void* d_out, int out_size, void* d_ws, size_t ws_size,
                              hipStream_t stream) {
    const float* data = (const float*)d_in[0];
    const int* a_idx  = (const int*)d_in[1];
    const int* a_len  = (const int*)d_in[2];
    const int* s_len  = (const int*)d_in[3];
    float* out        = (float*)d_out;

    const int n4 = out_size / 4;              // 26,214,400 / 4 = 6,553,600
    const int threads = 256;
    const int blocks = (n4 + threads - 1) / threads;   // 25,600 exact

    mask_mul_kernel<<<blocks, threads, 0, stream>>>(
        (const float4*)data, a_idx, a_len, s_len, (float4*)out);
}

// Round 2
// 180.906 us; speedup vs baseline: 1.0119x; 1.0119x over previous
//
#include <hip/hip_runtime.h>

// Problem: out(b,l,h) = data(b,l,h) * mask(b,l); B=512,L=512,H=100,C=40.
// mask: a_end = aI+aL;  l<a_end -> 1-(a_end-l)/C;  l<sL -> 1-(l-aI)/C; else 0.
// Memory-bound: 105 MB read + 105 MB write, floor ~33us @ 6.3 TB/s.
// Both streams are touch-once (>> 32MB L2) -> nontemporal hints.

constexpr int kL = 512;
constexpr int kH = 100;
constexpr float kInvC = 1.0f / 40.0f;

typedef float f32x4 __attribute__((ext_vector_type(4)));

__global__ __launch_bounds__(256) void mask_mul_kernel(
    const f32x4* __restrict__ data,
    const int* __restrict__ a_idx,
    const int* __restrict__ a_len,
    const int* __restrict__ s_len,
    f32x4* __restrict__ out)
{
    const int idx = blockIdx.x * blockDim.x + threadIdx.x;   // float4 index
    const int e   = idx * 4;                                  // element index
    // H=100 divisible by 4 => all 4 elements of this float4 share one (b,l)
    const int bl = e / kH;              // row index (magic-mul by 100)
    const int l  = bl & (kL - 1);
    const int b  = bl >> 9;             // L=512

    const int aI = a_idx[b];
    const int aE = aI + a_len[b];
    const int sL = s_len[b];

    float m;
    if (l < aE)       m = 1.0f - (float)(aE - l) * kInvC;
    else if (l < sL)  m = 1.0f - (float)(l - aI) * kInvC;
    else              m = 0.0f;

    f32x4 v = __builtin_nontemporal_load(&data[idx]);
    v *= m;
    __builtin_nontemporal_store(v, &out[idx]);
}

extern "C" void kernel_launch(void* const* d_in, const int* in_sizes, int n_in,
                              void* d_out, int out_size, void* d_ws, size_t ws_size,
                              hipStream_t stream) {
    const float* data = (const float*)d_in[0];
    const int* a_idx  = (const int*)d_in[1];
    const int* a_len  = (const int*)d_in[2];
    const int* s_len  = (const int*)d_in[3];
    float* out        = (float*)d_out;

    const int n4 = out_size / 4;              // 6,553,600 float4s
    const int threads = 256;
    const int blocks = (n4 + threads - 1) / threads;   // 25,600 exact

    mask_mul_kernel<<<blocks, threads, 0, stream>>>(
        (const f32x4*)data, a_idx, a_len, s_len, (f32x4*)out);
}